// Round 15
// baseline (309.997 us; speedup 1.0000x reference)
//
#include <hip/hip_runtime.h>
#include <hip/hip_fp16.h>
#include <hip/hip_cooperative_groups.h>
#include <math.h>

namespace cg = cooperative_groups;

#define N_NODES 100000
#define N_EDGES 3200000
#define NB 512            // dst buckets (max b = 510)
#define NPB 196           // nodes per bucket
#define CAP 7168          // per-bucket capacity (mean 6272, ~11 sigma margin)
#define EPB 12544         // edges per binning block -> grid 256 = 1 block/CU
#define NBLK ((N_EDGES + EPB - 1) / EPB)  // 256

#define FSCALE 1048576.0f
#define INV_FSCALE (1.0f / 1048576.0f)

__device__ inline float2 h2f2(unsigned int u) {
    __half2 h = *reinterpret_cast<__half2*>(&u);
    return make_float2(__low2float(h), __high2float(h));
}

__device__ inline int fx(float v) { return __float2int_rn(v * FSCALE); }

__global__ void k_zero(int* __restrict__ gcur) {
    int i = blockIdx.x * blockDim.x + threadIdx.x;
    if (i < NB) gcur[i] = 0;
}

// R14-proven two-pass counting sort with LDS staging + coalesced copy-out.
__global__ void __launch_bounds__(1024) k_bucket(
        const int* __restrict__ ei, int* __restrict__ gcur,
        unsigned int* __restrict__ bdata) {
    __shared__ unsigned int lds_pay[EPB];
    __shared__ int cnt[NB];
    __shared__ int gb[NB];
    __shared__ int sc[NB];
    __shared__ int psum[NB + 1];
    int blk = blockIdx.x, tid = threadIdx.x;
    int e0 = blk * EPB;
    int ecnt = min(EPB, N_EDGES - e0);
    const int* dst = ei + N_EDGES + e0;
    const int* src = ei + e0;

    if (tid < NB) cnt[tid] = 0;
    __syncthreads();
    for (int i = tid; i < ecnt; i += 4096) {
        int i1 = i + 1024, i2 = i + 2048, i3 = i + 3072;
        int d0 = dst[i];
        int d1 = (i1 < ecnt) ? dst[i1] : 0;
        int d2 = (i2 < ecnt) ? dst[i2] : 0;
        int d3 = (i3 < ecnt) ? dst[i3] : 0;
        atomicAdd(&cnt[d0 / NPB], 1);
        if (i1 < ecnt) atomicAdd(&cnt[d1 / NPB], 1);
        if (i2 < ecnt) atomicAdd(&cnt[d2 / NPB], 1);
        if (i3 < ecnt) atomicAdd(&cnt[d3 / NPB], 1);
    }
    __syncthreads();
    if (tid < NB) {
        int c = cnt[tid];
        gb[tid] = (c > 0) ? atomicAdd(&gcur[tid], c) : 0;
        sc[tid] = c;
    }
    __syncthreads();
    for (int off = 1; off < NB; off <<= 1) {
        int v = 0;
        if (tid < NB && tid >= off) v = sc[tid - off];
        __syncthreads();
        if (tid < NB) sc[tid] += v;
        __syncthreads();
    }
    if (tid < NB) {
        psum[tid + 1] = sc[tid];
        if (tid == 0) psum[0] = 0;
        cnt[tid] = 0;
    }
    __syncthreads();
    for (int i = tid; i < ecnt; i += 4096) {
        int i1 = i + 1024, i2 = i + 2048, i3 = i + 3072;
        int d0 = dst[i];
        int s0 = src[i];
        int d1 = (i1 < ecnt) ? dst[i1] : 0;
        int s1 = (i1 < ecnt) ? src[i1] : 0;
        int d2 = (i2 < ecnt) ? dst[i2] : 0;
        int s2 = (i2 < ecnt) ? src[i2] : 0;
        int d3 = (i3 < ecnt) ? dst[i3] : 0;
        int s3 = (i3 < ecnt) ? src[i3] : 0;
        {
            int b = d0 / NPB, dl = d0 - b * NPB;
            int lp = atomicAdd(&cnt[b], 1) + psum[b];
            lds_pay[lp] = ((unsigned)dl << 17) | (unsigned)s0;
        }
        if (i1 < ecnt) {
            int b = d1 / NPB, dl = d1 - b * NPB;
            int lp = atomicAdd(&cnt[b], 1) + psum[b];
            lds_pay[lp] = ((unsigned)dl << 17) | (unsigned)s1;
        }
        if (i2 < ecnt) {
            int b = d2 / NPB, dl = d2 - b * NPB;
            int lp = atomicAdd(&cnt[b], 1) + psum[b];
            lds_pay[lp] = ((unsigned)dl << 17) | (unsigned)s2;
        }
        if (i3 < ecnt) {
            int b = d3 / NPB, dl = d3 - b * NPB;
            int lp = atomicAdd(&cnt[b], 1) + psum[b];
            lds_pay[lp] = ((unsigned)dl << 17) | (unsigned)s3;
        }
    }
    __syncthreads();
    for (int e = tid; e < ecnt; e += 1024) {
        int lo = 0, hi = NB;
        while (hi - lo > 1) {
            int mid = (lo + hi) >> 1;
            if (psum[mid] <= e) lo = mid; else hi = mid;
        }
        int gp = gb[lo] + (e - psum[lo]);
        if (gp < CAP) bdata[(size_t)lo * CAP + gp] = lds_pay[e];
    }
}

// Cooperative fused consumer: one block per bucket; payload LDS-resident across
// all three phases; grid-wide syncs replace kernel boundaries.
__global__ void __launch_bounds__(512) k_fused(
        const int* __restrict__ gcur, const unsigned int* __restrict__ bdata,
        const float* __restrict__ x, __half2* __restrict__ xh,
        uint4* __restrict__ th, const float* __restrict__ W1,
        const float* __restrict__ b1, const float* __restrict__ W2,
        const float* __restrict__ b2, float* __restrict__ out) {
    __shared__ unsigned int pay[CAP];   // 28.7 KB
    __shared__ int acc[NPB * 7];        // 5.5 KB (reused per phase)
    cg::grid_group grid = cg::this_grid();
    int b = blockIdx.x, tid = threadIdx.x;
    int n = min(gcur[b], CAP);
    const unsigned int* p = bdata + (size_t)b * CAP;
    for (int e = tid; e < n; e += 512) pay[e] = p[e];   // burst-load once
    // ---- phase 1: degree -> xh ----
    for (int j = tid; j < NPB; j += 512) acc[j] = 0;
    __syncthreads();
    for (int e = tid; e < n; e += 512) atomicAdd(&acc[pay[e] >> 17], 1);
    __syncthreads();
    int base = b * NPB;
    for (int j = tid; j < NPB; j += 512) {
        int i = base + j;
        if (i < N_NODES) {
            float di = rsqrtf((float)acc[j] + 1.0f);
            xh[2 * i + 0] = __floats2half2_rn(di * x[3 * i + 0], di * x[3 * i + 1]);
            xh[2 * i + 1] = __floats2half2_rn(di * x[3 * i + 2], di);
        }
    }
    __threadfence();
    grid.sync();
    // ---- phase 2: layer 1 -> th ----
    const uint2* xg = (const uint2*)xh;
    for (int j = tid; j < NPB * 3; j += 512) acc[j] = 0;
    __syncthreads();
    for (int e = tid; e < n; e += 2048) {
        int e1 = e + 512, e2 = e + 1024, e3 = e + 1536;
        unsigned int pk0 = pay[e];
        unsigned int pk1 = (e1 < n) ? pay[e1] : 0u;
        unsigned int pk2 = (e2 < n) ? pay[e2] : 0u;
        unsigned int pk3 = (e3 < n) ? pay[e3] : 0u;
        uint2 g0 = xg[pk0 & 0x1FFFF];
        uint2 g1 = (e1 < n) ? xg[pk1 & 0x1FFFF] : make_uint2(0u, 0u);
        uint2 g2 = (e2 < n) ? xg[pk2 & 0x1FFFF] : make_uint2(0u, 0u);
        uint2 g3 = (e3 < n) ? xg[pk3 & 0x1FFFF] : make_uint2(0u, 0u);
        {
            int dl = pk0 >> 17;
            float2 f01 = h2f2(g0.x), f2w = h2f2(g0.y);
            atomicAdd(&acc[dl * 3 + 0], fx(f01.x));
            atomicAdd(&acc[dl * 3 + 1], fx(f01.y));
            atomicAdd(&acc[dl * 3 + 2], fx(f2w.x));
        }
        if (e1 < n) {
            int dl = pk1 >> 17;
            float2 f01 = h2f2(g1.x), f2w = h2f2(g1.y);
            atomicAdd(&acc[dl * 3 + 0], fx(f01.x));
            atomicAdd(&acc[dl * 3 + 1], fx(f01.y));
            atomicAdd(&acc[dl * 3 + 2], fx(f2w.x));
        }
        if (e2 < n) {
            int dl = pk2 >> 17;
            float2 f01 = h2f2(g2.x), f2w = h2f2(g2.y);
            atomicAdd(&acc[dl * 3 + 0], fx(f01.x));
            atomicAdd(&acc[dl * 3 + 1], fx(f01.y));
            atomicAdd(&acc[dl * 3 + 2], fx(f2w.x));
        }
        if (e3 < n) {
            int dl = pk3 >> 17;
            float2 f01 = h2f2(g3.x), f2w = h2f2(g3.y);
            atomicAdd(&acc[dl * 3 + 0], fx(f01.x));
            atomicAdd(&acc[dl * 3 + 1], fx(f01.y));
            atomicAdd(&acc[dl * 3 + 2], fx(f2w.x));
        }
    }
    __syncthreads();
    for (int j = tid; j < NPB; j += 512) {
        int i = base + j;
        if (i >= N_NODES) continue;
        uint2 gi = xg[i];
        float2 f01 = h2f2(gi.x);
        float2 f2w = h2f2(gi.y);
        float di = f2w.y;
        float a0 = di * ((float)acc[j * 3 + 0] * INV_FSCALE + f01.x);
        float a1 = di * ((float)acc[j * 3 + 1] * INV_FSCALE + f01.y);
        float a2 = di * ((float)acc[j * 3 + 2] * INV_FSCALE + f2w.x);
        float r[16];
#pragma unroll
        for (int k = 0; k < 16; ++k)
            r[k] = fmaxf(a0 * W1[k] + a1 * W1[16 + k] + a2 * W1[32 + k] + b1[k], 0.0f);
        float t[7];
#pragma unroll
        for (int c = 0; c < 7; ++c) {
            float v = 0.0f;
#pragma unroll
            for (int k = 0; k < 16; ++k) v += r[k] * W2[7 * k + c];
            t[c] = di * v;
        }
        __half2 h0 = __floats2half2_rn(t[0], t[1]);
        __half2 h1 = __floats2half2_rn(t[2], t[3]);
        __half2 h2 = __floats2half2_rn(t[4], t[5]);
        __half2 h3 = __floats2half2_rn(t[6], di);
        uint4 pk;
        pk.x = *reinterpret_cast<unsigned int*>(&h0);
        pk.y = *reinterpret_cast<unsigned int*>(&h1);
        pk.z = *reinterpret_cast<unsigned int*>(&h2);
        pk.w = *reinterpret_cast<unsigned int*>(&h3);
        th[i] = pk;
    }
    __threadfence();
    grid.sync();
    // ---- phase 3: layer 2 -> log_softmax -> out ----
    for (int j = tid; j < NPB * 7; j += 512) acc[j] = 0;
    __syncthreads();
    for (int e = tid; e < n; e += 2048) {
        int e1 = e + 512, e2 = e + 1024, e3 = e + 1536;
        unsigned int pk0 = pay[e];
        unsigned int pk1 = (e1 < n) ? pay[e1] : 0u;
        unsigned int pk2 = (e2 < n) ? pay[e2] : 0u;
        unsigned int pk3 = (e3 < n) ? pay[e3] : 0u;
        uint4 g0 = th[pk0 & 0x1FFFF];
        uint4 g1 = (e1 < n) ? th[pk1 & 0x1FFFF] : make_uint4(0u, 0u, 0u, 0u);
        uint4 g2 = (e2 < n) ? th[pk2 & 0x1FFFF] : make_uint4(0u, 0u, 0u, 0u);
        uint4 g3 = (e3 < n) ? th[pk3 & 0x1FFFF] : make_uint4(0u, 0u, 0u, 0u);
        {
            int dl = pk0 >> 17;
            float2 u0 = h2f2(g0.x), u1 = h2f2(g0.y), u2 = h2f2(g0.z), u3 = h2f2(g0.w);
            atomicAdd(&acc[dl * 7 + 0], fx(u0.x));
            atomicAdd(&acc[dl * 7 + 1], fx(u0.y));
            atomicAdd(&acc[dl * 7 + 2], fx(u1.x));
            atomicAdd(&acc[dl * 7 + 3], fx(u1.y));
            atomicAdd(&acc[dl * 7 + 4], fx(u2.x));
            atomicAdd(&acc[dl * 7 + 5], fx(u2.y));
            atomicAdd(&acc[dl * 7 + 6], fx(u3.x));
        }
        if (e1 < n) {
            int dl = pk1 >> 17;
            float2 u0 = h2f2(g1.x), u1 = h2f2(g1.y), u2 = h2f2(g1.z), u3 = h2f2(g1.w);
            atomicAdd(&acc[dl * 7 + 0], fx(u0.x));
            atomicAdd(&acc[dl * 7 + 1], fx(u0.y));
            atomicAdd(&acc[dl * 7 + 2], fx(u1.x));
            atomicAdd(&acc[dl * 7 + 3], fx(u1.y));
            atomicAdd(&acc[dl * 7 + 4], fx(u2.x));
            atomicAdd(&acc[dl * 7 + 5], fx(u2.y));
            atomicAdd(&acc[dl * 7 + 6], fx(u3.x));
        }
        if (e2 < n) {
            int dl = pk2 >> 17;
            float2 u0 = h2f2(g2.x), u1 = h2f2(g2.y), u2 = h2f2(g2.z), u3 = h2f2(g2.w);
            atomicAdd(&acc[dl * 7 + 0], fx(u0.x));
            atomicAdd(&acc[dl * 7 + 1], fx(u0.y));
            atomicAdd(&acc[dl * 7 + 2], fx(u1.x));
            atomicAdd(&acc[dl * 7 + 3], fx(u1.y));
            atomicAdd(&acc[dl * 7 + 4], fx(u2.x));
            atomicAdd(&acc[dl * 7 + 5], fx(u2.y));
            atomicAdd(&acc[dl * 7 + 6], fx(u3.x));
        }
        if (e3 < n) {
            int dl = pk3 >> 17;
            float2 u0 = h2f2(g3.x), u1 = h2f2(g3.y), u2 = h2f2(g3.z), u3 = h2f2(g3.w);
            atomicAdd(&acc[dl * 7 + 0], fx(u0.x));
            atomicAdd(&acc[dl * 7 + 1], fx(u0.y));
            atomicAdd(&acc[dl * 7 + 2], fx(u1.x));
            atomicAdd(&acc[dl * 7 + 3], fx(u1.y));
            atomicAdd(&acc[dl * 7 + 4], fx(u2.x));
            atomicAdd(&acc[dl * 7 + 5], fx(u2.y));
            atomicAdd(&acc[dl * 7 + 6], fx(u3.x));
        }
    }
    __syncthreads();
    for (int j = tid; j < NPB; j += 512) {
        int i = base + j;
        if (i >= N_NODES) continue;
        uint4 gi = th[i];
        float2 t0 = h2f2(gi.x), t1 = h2f2(gi.y), t2 = h2f2(gi.z), t3 = h2f2(gi.w);
        float di = t3.y;
        float thv[7] = {t0.x, t0.y, t1.x, t1.y, t2.x, t2.y, t3.x};
        float v[7];
        float m = -1e30f;
#pragma unroll
        for (int c = 0; c < 7; ++c) {
            v[c] = di * ((float)acc[j * 7 + c] * INV_FSCALE + thv[c]) + b2[c];
            m = fmaxf(m, v[c]);
        }
        float sum = 0.0f;
#pragma unroll
        for (int c = 0; c < 7; ++c) sum += expf(v[c] - m);
        float lse = m + logf(sum);
#pragma unroll
        for (int c = 0; c < 7; ++c) out[7 * i + c] = v[c] - lse;
    }
}

extern "C" void kernel_launch(void* const* d_in, const int* in_sizes, int n_in,
                              void* d_out, int out_size, void* d_ws, size_t ws_size,
                              hipStream_t stream) {
    const float* x  = (const float*)d_in[0];
    const int*   ei = (const int*)d_in[1];  // [2,E] flat int32: src then dst
    const float* W1 = (const float*)d_in[2];
    const float* b1 = (const float*)d_in[3];
    const float* W2 = (const float*)d_in[4];
    const float* b2 = (const float*)d_in[5];
    float* out = (float*)d_out;

    char* ws = (char*)d_ws;
    int*          gcur  = (int*)ws;          ws += 4096;
    __half2*      xh    = (__half2*)ws;      ws += (size_t)N_NODES * 8;
    uint4*        th    = (uint4*)ws;        ws += (size_t)N_NODES * 16;
    unsigned int* bdata = (unsigned int*)ws;

    k_zero<<<2, 256, 0, stream>>>(gcur);
    k_bucket<<<NBLK, 1024, 0, stream>>>(ei, gcur, bdata);

    void* args[] = {(void*)&gcur, (void*)&bdata, (void*)&x, (void*)&xh,
                    (void*)&th, (void*)&W1, (void*)&b1, (void*)&W2,
                    (void*)&b2, (void*)&out};
    hipLaunchCooperativeKernel((void*)k_fused, dim3(NB), dim3(512), args, 0, stream);
}

// Round 16
// 80.409 us; speedup vs baseline: 3.8553x; 3.8553x over previous
//
#include <hip/hip_runtime.h>
#include <hip/hip_fp16.h>
#include <math.h>

#define N_NODES 100000
#define N_EDGES 3200000
#define NB 512            // dst buckets (max b = 510)
#define NPB 196           // nodes per bucket
#define CAP 7168          // per-bucket capacity (mean 6272, ~11 sigma margin)
#define EPB 6272          // edges per binning block (512 thr, 4 blocks/CU co-resident)
#define NBLK ((N_EDGES + EPB - 1) / EPB)  // 511

#define FSCALE 1048576.0f           // 2^20 fixed-point scale for LDS accumulation
#define INV_FSCALE (1.0f / 1048576.0f)

// ws: gcur[NB] int | xh __half2[2N] (8B/node) | th uint4[N] (16B/node) | bdata u32[NB*CAP]

__device__ inline float2 h2f2(unsigned int u) {
    __half2 h = *reinterpret_cast<__half2*>(&u);
    return make_float2(__low2float(h), __high2float(h));
}

__device__ inline int fx(float v) { return __float2int_rn(v * FSCALE); }

__global__ void k_zero(int* __restrict__ gcur) {
    int i = blockIdx.x * blockDim.x + threadIdx.x;
    if (i < NB) gcur[i] = 0;
}

// two-pass block-local counting sort with LDS staging + coalesced copy-out.
// 512 threads / 6272 edges per block -> ~35 KB LDS -> 4 blocks/CU co-resident.
__global__ void __launch_bounds__(512) k_bucket(
        const int* __restrict__ ei, int* __restrict__ gcur,
        unsigned int* __restrict__ bdata) {
    __shared__ unsigned int lds_pay[EPB];   // 25 KB
    __shared__ int cnt[NB];
    __shared__ int gb[NB];
    __shared__ int sc[NB];
    __shared__ int psum[NB + 1];
    int blk = blockIdx.x, tid = threadIdx.x;  // 512 threads
    int e0 = blk * EPB;
    int ecnt = min(EPB, N_EDGES - e0);
    const int* dst = ei + N_EDGES + e0;
    const int* src = ei + e0;

    cnt[tid] = 0;
    __syncthreads();
    // pass A: histogram of dst buckets, 4 independent loads in flight
    for (int i = tid; i < ecnt; i += 2048) {
        int i1 = i + 512, i2 = i + 1024, i3 = i + 1536;
        int d0 = dst[i];
        int d1 = (i1 < ecnt) ? dst[i1] : 0;
        int d2 = (i2 < ecnt) ? dst[i2] : 0;
        int d3 = (i3 < ecnt) ? dst[i3] : 0;
        atomicAdd(&cnt[d0 / NPB], 1);
        if (i1 < ecnt) atomicAdd(&cnt[d1 / NPB], 1);
        if (i2 < ecnt) atomicAdd(&cnt[d2 / NPB], 1);
        if (i3 < ecnt) atomicAdd(&cnt[d3 / NPB], 1);
    }
    __syncthreads();
    // claim exact runs; seed the scan array
    {
        int c = cnt[tid];
        gb[tid] = (c > 0) ? atomicAdd(&gcur[tid], c) : 0;
        sc[tid] = c;
    }
    __syncthreads();
    // inclusive Hillis-Steele scan of sc[0..NB) (512 entries, 9 steps)
    for (int off = 1; off < NB; off <<= 1) {
        int v = (tid >= off) ? sc[tid - off] : 0;
        __syncthreads();
        sc[tid] += v;
        __syncthreads();
    }
    {
        psum[tid + 1] = sc[tid];
        if (tid == 0) psum[0] = 0;
        cnt[tid] = 0;  // reuse as local placement cursor
    }
    __syncthreads();
    // pass B: place payloads into LDS at psum[b] + local_pos (random LDS writes)
    for (int i = tid; i < ecnt; i += 2048) {
        int i1 = i + 512, i2 = i + 1024, i3 = i + 1536;
        int d0 = dst[i];
        int s0 = src[i];
        int d1 = (i1 < ecnt) ? dst[i1] : 0;
        int s1 = (i1 < ecnt) ? src[i1] : 0;
        int d2 = (i2 < ecnt) ? dst[i2] : 0;
        int s2 = (i2 < ecnt) ? src[i2] : 0;
        int d3 = (i3 < ecnt) ? dst[i3] : 0;
        int s3 = (i3 < ecnt) ? src[i3] : 0;
        {
            int b = d0 / NPB, dl = d0 - b * NPB;
            int lp = atomicAdd(&cnt[b], 1) + psum[b];
            lds_pay[lp] = ((unsigned)dl << 17) | (unsigned)s0;
        }
        if (i1 < ecnt) {
            int b = d1 / NPB, dl = d1 - b * NPB;
            int lp = atomicAdd(&cnt[b], 1) + psum[b];
            lds_pay[lp] = ((unsigned)dl << 17) | (unsigned)s1;
        }
        if (i2 < ecnt) {
            int b = d2 / NPB, dl = d2 - b * NPB;
            int lp = atomicAdd(&cnt[b], 1) + psum[b];
            lds_pay[lp] = ((unsigned)dl << 17) | (unsigned)s2;
        }
        if (i3 < ecnt) {
            int b = d3 / NPB, dl = d3 - b * NPB;
            int lp = atomicAdd(&cnt[b], 1) + psum[b];
            lds_pay[lp] = ((unsigned)dl << 17) | (unsigned)s3;
        }
    }
    __syncthreads();
    // copy-out: consecutive threads -> consecutive positions of concatenated runs
    for (int e = tid; e < ecnt; e += 512) {
        // binary search: bucket b with psum[b] <= e < psum[b+1]
        int lo = 0, hi = NB;
        while (hi - lo > 1) {
            int mid = (lo + hi) >> 1;
            if (psum[mid] <= e) lo = mid; else hi = mid;
        }
        int gp = gb[lo] + (e - psum[lo]);
        if (gp < CAP) bdata[(size_t)lo * CAP + gp] = lds_pay[e];
    }
}

// per-bucket degree histogram -> xh[i] = fp16{di*x0, di*x1, di*x2, di}
__global__ void k_deg(const int* __restrict__ gcur, const unsigned int* __restrict__ bdata,
                      const float* __restrict__ x, __half2* __restrict__ xh) {
    __shared__ int cnt[NPB];
    int b = blockIdx.x, t = threadIdx.x;
    for (int j = t; j < NPB; j += 512) cnt[j] = 0;
    __syncthreads();
    int n = min(gcur[b], CAP);
    const unsigned int* p = bdata + (size_t)b * CAP;
    for (int e = t; e < n; e += 512) atomicAdd(&cnt[p[e] >> 17], 1);
    __syncthreads();
    int base = b * NPB;
    for (int j = t; j < NPB; j += 512) {
        int i = base + j;
        if (i < N_NODES) {
            float di = rsqrtf((float)cnt[j] + 1.0f);
            xh[2 * i + 0] = __floats2half2_rn(di * x[3 * i + 0], di * x[3 * i + 1]);
            xh[2 * i + 1] = __floats2half2_rn(di * x[3 * i + 2], di);
        }
    }
}

// layer-1: LDS fixed-point accumulate sum_s (di_s*x_s) via native ds_add_u32,
// 4-way ILP on the gather; fused W1/b1/relu/W2 -> th[i] = fp16{di*t[0..6], di}
__global__ void __launch_bounds__(1024) k_l1(
        const int* __restrict__ gcur, const unsigned int* __restrict__ bdata,
        const __half2* __restrict__ xh, const float* __restrict__ W1,
        const float* __restrict__ b1, const float* __restrict__ W2,
        uint4* __restrict__ th) {
    __shared__ int a[NPB * 3];
    int b = blockIdx.x, tid = threadIdx.x;
    for (int j = tid; j < NPB * 3; j += 1024) a[j] = 0;
    __syncthreads();
    int n = min(gcur[b], CAP);
    const unsigned int* p = bdata + (size_t)b * CAP;
    const uint2* xg = (const uint2*)xh;
    for (int e = tid; e < n; e += 4096) {
        int e1 = e + 1024, e2 = e + 2048, e3 = e + 3072;
        unsigned int pk0 = p[e];
        unsigned int pk1 = (e1 < n) ? p[e1] : 0u;
        unsigned int pk2 = (e2 < n) ? p[e2] : 0u;
        unsigned int pk3 = (e3 < n) ? p[e3] : 0u;
        uint2 g0 = xg[pk0 & 0x1FFFF];
        uint2 g1 = (e1 < n) ? xg[pk1 & 0x1FFFF] : make_uint2(0u, 0u);
        uint2 g2 = (e2 < n) ? xg[pk2 & 0x1FFFF] : make_uint2(0u, 0u);
        uint2 g3 = (e3 < n) ? xg[pk3 & 0x1FFFF] : make_uint2(0u, 0u);
        {
            int dl = pk0 >> 17;
            float2 f01 = h2f2(g0.x), f2w = h2f2(g0.y);
            atomicAdd(&a[dl * 3 + 0], fx(f01.x));
            atomicAdd(&a[dl * 3 + 1], fx(f01.y));
            atomicAdd(&a[dl * 3 + 2], fx(f2w.x));
        }
        if (e1 < n) {
            int dl = pk1 >> 17;
            float2 f01 = h2f2(g1.x), f2w = h2f2(g1.y);
            atomicAdd(&a[dl * 3 + 0], fx(f01.x));
            atomicAdd(&a[dl * 3 + 1], fx(f01.y));
            atomicAdd(&a[dl * 3 + 2], fx(f2w.x));
        }
        if (e2 < n) {
            int dl = pk2 >> 17;
            float2 f01 = h2f2(g2.x), f2w = h2f2(g2.y);
            atomicAdd(&a[dl * 3 + 0], fx(f01.x));
            atomicAdd(&a[dl * 3 + 1], fx(f01.y));
            atomicAdd(&a[dl * 3 + 2], fx(f2w.x));
        }
        if (e3 < n) {
            int dl = pk3 >> 17;
            float2 f01 = h2f2(g3.x), f2w = h2f2(g3.y);
            atomicAdd(&a[dl * 3 + 0], fx(f01.x));
            atomicAdd(&a[dl * 3 + 1], fx(f01.y));
            atomicAdd(&a[dl * 3 + 2], fx(f2w.x));
        }
    }
    __syncthreads();
    int base = b * NPB;
    for (int j = tid; j < NPB; j += 1024) {
        int i = base + j;
        if (i >= N_NODES) continue;
        uint2 gi = xg[i];
        float2 f01 = h2f2(gi.x);
        float2 f2w = h2f2(gi.y);
        float di = f2w.y;
        float a0 = di * ((float)a[j * 3 + 0] * INV_FSCALE + f01.x);
        float a1 = di * ((float)a[j * 3 + 1] * INV_FSCALE + f01.y);
        float a2 = di * ((float)a[j * 3 + 2] * INV_FSCALE + f2w.x);
        float r[16];
#pragma unroll
        for (int k = 0; k < 16; ++k)
            r[k] = fmaxf(a0 * W1[k] + a1 * W1[16 + k] + a2 * W1[32 + k] + b1[k], 0.0f);
        float t[7];
#pragma unroll
        for (int c = 0; c < 7; ++c) {
            float v = 0.0f;
#pragma unroll
            for (int k = 0; k < 16; ++k) v += r[k] * W2[7 * k + c];
            t[c] = di * v;
        }
        __half2 h0 = __floats2half2_rn(t[0], t[1]);
        __half2 h1 = __floats2half2_rn(t[2], t[3]);
        __half2 h2 = __floats2half2_rn(t[4], t[5]);
        __half2 h3 = __floats2half2_rn(t[6], di);
        uint4 pk;
        pk.x = *reinterpret_cast<unsigned int*>(&h0);
        pk.y = *reinterpret_cast<unsigned int*>(&h1);
        pk.z = *reinterpret_cast<unsigned int*>(&h2);
        pk.w = *reinterpret_cast<unsigned int*>(&h3);
        th[i] = pk;
    }
}

// layer-2: one 16B gather/edge with 4-way ILP, LDS fixed-point accumulate 7 values,
// then bias + log_softmax -> out
__global__ void __launch_bounds__(1024) k_l2(
        const int* __restrict__ gcur, const unsigned int* __restrict__ bdata,
        const uint4* __restrict__ th, const float* __restrict__ b2,
        float* __restrict__ out) {
    __shared__ int a[NPB * 7];
    int b = blockIdx.x, tid = threadIdx.x;
    for (int j = tid; j < NPB * 7; j += 1024) a[j] = 0;
    __syncthreads();
    int n = min(gcur[b], CAP);
    const unsigned int* p = bdata + (size_t)b * CAP;
    for (int e = tid; e < n; e += 4096) {
        int e1 = e + 1024, e2 = e + 2048, e3 = e + 3072;
        unsigned int pk0 = p[e];
        unsigned int pk1 = (e1 < n) ? p[e1] : 0u;
        unsigned int pk2 = (e2 < n) ? p[e2] : 0u;
        unsigned int pk3 = (e3 < n) ? p[e3] : 0u;
        uint4 g0 = th[pk0 & 0x1FFFF];
        uint4 g1 = (e1 < n) ? th[pk1 & 0x1FFFF] : make_uint4(0u, 0u, 0u, 0u);
        uint4 g2 = (e2 < n) ? th[pk2 & 0x1FFFF] : make_uint4(0u, 0u, 0u, 0u);
        uint4 g3 = (e3 < n) ? th[pk3 & 0x1FFFF] : make_uint4(0u, 0u, 0u, 0u);
        {
            int dl = pk0 >> 17;
            float2 u0 = h2f2(g0.x), u1 = h2f2(g0.y), u2 = h2f2(g0.z), u3 = h2f2(g0.w);
            atomicAdd(&a[dl * 7 + 0], fx(u0.x));
            atomicAdd(&a[dl * 7 + 1], fx(u0.y));
            atomicAdd(&a[dl * 7 + 2], fx(u1.x));
            atomicAdd(&a[dl * 7 + 3], fx(u1.y));
            atomicAdd(&a[dl * 7 + 4], fx(u2.x));
            atomicAdd(&a[dl * 7 + 5], fx(u2.y));
            atomicAdd(&a[dl * 7 + 6], fx(u3.x));
        }
        if (e1 < n) {
            int dl = pk1 >> 17;
            float2 u0 = h2f2(g1.x), u1 = h2f2(g1.y), u2 = h2f2(g1.z), u3 = h2f2(g1.w);
            atomicAdd(&a[dl * 7 + 0], fx(u0.x));
            atomicAdd(&a[dl * 7 + 1], fx(u0.y));
            atomicAdd(&a[dl * 7 + 2], fx(u1.x));
            atomicAdd(&a[dl * 7 + 3], fx(u1.y));
            atomicAdd(&a[dl * 7 + 4], fx(u2.x));
            atomicAdd(&a[dl * 7 + 5], fx(u2.y));
            atomicAdd(&a[dl * 7 + 6], fx(u3.x));
        }
        if (e2 < n) {
            int dl = pk2 >> 17;
            float2 u0 = h2f2(g2.x), u1 = h2f2(g2.y), u2 = h2f2(g2.z), u3 = h2f2(g2.w);
            atomicAdd(&a[dl * 7 + 0], fx(u0.x));
            atomicAdd(&a[dl * 7 + 1], fx(u0.y));
            atomicAdd(&a[dl * 7 + 2], fx(u1.x));
            atomicAdd(&a[dl * 7 + 3], fx(u1.y));
            atomicAdd(&a[dl * 7 + 4], fx(u2.x));
            atomicAdd(&a[dl * 7 + 5], fx(u2.y));
            atomicAdd(&a[dl * 7 + 6], fx(u3.x));
        }
        if (e3 < n) {
            int dl = pk3 >> 17;
            float2 u0 = h2f2(g3.x), u1 = h2f2(g3.y), u2 = h2f2(g3.z), u3 = h2f2(g3.w);
            atomicAdd(&a[dl * 7 + 0], fx(u0.x));
            atomicAdd(&a[dl * 7 + 1], fx(u0.y));
            atomicAdd(&a[dl * 7 + 2], fx(u1.x));
            atomicAdd(&a[dl * 7 + 3], fx(u1.y));
            atomicAdd(&a[dl * 7 + 4], fx(u2.x));
            atomicAdd(&a[dl * 7 + 5], fx(u2.y));
            atomicAdd(&a[dl * 7 + 6], fx(u3.x));
        }
    }
    __syncthreads();
    int base = b * NPB;
    for (int j = tid; j < NPB; j += 1024) {
        int i = base + j;
        if (i >= N_NODES) continue;
        uint4 gi = th[i];
        float2 t0 = h2f2(gi.x), t1 = h2f2(gi.y), t2 = h2f2(gi.z), t3 = h2f2(gi.w);
        float di = t3.y;
        float thv[7] = {t0.x, t0.y, t1.x, t1.y, t2.x, t2.y, t3.x};
        float v[7];
        float m = -1e30f;
#pragma unroll
        for (int c = 0; c < 7; ++c) {
            v[c] = di * ((float)a[j * 7 + c] * INV_FSCALE + thv[c]) + b2[c];
            m = fmaxf(m, v[c]);
        }
        float sum = 0.0f;
#pragma unroll
        for (int c = 0; c < 7; ++c) sum += expf(v[c] - m);
        float lse = m + logf(sum);
#pragma unroll
        for (int c = 0; c < 7; ++c) out[7 * i + c] = v[c] - lse;
    }
}

extern "C" void kernel_launch(void* const* d_in, const int* in_sizes, int n_in,
                              void* d_out, int out_size, void* d_ws, size_t ws_size,
                              hipStream_t stream) {
    const float* x  = (const float*)d_in[0];
    const int*   ei = (const int*)d_in[1];  // [2,E] flat int32: src then dst
    const float* W1 = (const float*)d_in[2];
    const float* b1 = (const float*)d_in[3];
    const float* W2 = (const float*)d_in[4];
    const float* b2 = (const float*)d_in[5];
    float* out = (float*)d_out;

    char* ws = (char*)d_ws;
    int*          gcur  = (int*)ws;          ws += 4096;                    // NB*4, 64B-aligned
    __half2*      xh    = (__half2*)ws;      ws += (size_t)N_NODES * 8;     // 0.8 MB
    uint4*        th    = (uint4*)ws;        ws += (size_t)N_NODES * 16;    // 1.6 MB
    unsigned int* bdata = (unsigned int*)ws;                                // 14.7 MB

    k_zero<<<2, 256, 0, stream>>>(gcur);
    k_bucket<<<NBLK, 512, 0, stream>>>(ei, gcur, bdata);
    k_deg<<<NB, 512, 0, stream>>>(gcur, bdata, x, xh);
    k_l1<<<NB, 1024, 0, stream>>>(gcur, bdata, xh, W1, b1, W2, th);
    k_l2<<<NB, 1024, 0, stream>>>(gcur, bdata, th, b2, out);
}

// Round 17
// 68.063 us; speedup vs baseline: 4.5546x; 1.1814x over previous
//
#include <hip/hip_runtime.h>
#include <hip/hip_fp16.h>
#include <math.h>

#define N_NODES 100000
#define N_EDGES 3200000
#define NB 512            // dst buckets (max b = 510)
#define NPB 196           // nodes per bucket
#define CAP 7168          // per-bucket capacity (mean 6272, ~11 sigma margin)
#define EPB 12544         // edges per binning block -> grid 256 = 1 block/CU
#define NBLK ((N_EDGES + EPB - 1) / EPB)  // 256
#define BADIDX 0xFFFFFFFFu

#define FSCALE 1048576.0f           // 2^20 fixed-point scale for LDS accumulation
#define INV_FSCALE (1.0f / 1048576.0f)

// ws: gcur[NB] int | xh __half2[2N] (8B/node) | th uint4[N] (16B/node) | bdata u32[NB*CAP]

__device__ inline float2 h2f2(unsigned int u) {
    __half2 h = *reinterpret_cast<__half2*>(&u);
    return make_float2(__low2float(h), __high2float(h));
}

__device__ inline int fx(float v) { return __float2int_rn(v * FSCALE); }

// two-pass block-local counting sort with LDS staging; copy-out uses a
// precomputed direct global index (no binary search).
__global__ void __launch_bounds__(1024) k_bucket(
        const int* __restrict__ ei, int* __restrict__ gcur,
        unsigned int* __restrict__ bdata) {
    __shared__ unsigned int lds_pay[EPB];   // 50 KB sorted payloads
    __shared__ unsigned int lds_idx[EPB];   // 50 KB direct global indices
    __shared__ int cnt[NB];
    __shared__ int gb[NB];
    __shared__ int sc[NB];
    __shared__ int psum[NB + 1];
    int blk = blockIdx.x, tid = threadIdx.x;  // 1024 threads
    int e0 = blk * EPB;
    int ecnt = min(EPB, N_EDGES - e0);
    const int* dst = ei + N_EDGES + e0;
    const int* src = ei + e0;

    if (tid < NB) cnt[tid] = 0;
    __syncthreads();
    // pass A: histogram of dst buckets, 4 independent loads in flight
    for (int i = tid; i < ecnt; i += 4096) {
        int i1 = i + 1024, i2 = i + 2048, i3 = i + 3072;
        int d0 = dst[i];
        int d1 = (i1 < ecnt) ? dst[i1] : 0;
        int d2 = (i2 < ecnt) ? dst[i2] : 0;
        int d3 = (i3 < ecnt) ? dst[i3] : 0;
        atomicAdd(&cnt[d0 / NPB], 1);
        if (i1 < ecnt) atomicAdd(&cnt[d1 / NPB], 1);
        if (i2 < ecnt) atomicAdd(&cnt[d2 / NPB], 1);
        if (i3 < ecnt) atomicAdd(&cnt[d3 / NPB], 1);
    }
    __syncthreads();
    // claim exact runs; seed scan
    if (tid < NB) {
        int c = cnt[tid];
        gb[tid] = (c > 0) ? atomicAdd(&gcur[tid], c) : 0;
        sc[tid] = c;
    }
    __syncthreads();
    // inclusive Hillis-Steele scan of sc[0..NB) (512 entries, 9 steps)
    for (int off = 1; off < NB; off <<= 1) {
        int v = 0;
        if (tid < NB && tid >= off) v = sc[tid - off];
        __syncthreads();
        if (tid < NB) sc[tid] += v;
        __syncthreads();
    }
    if (tid < NB) {
        psum[tid + 1] = sc[tid];
        if (tid == 0) psum[0] = 0;
        cnt[tid] = 0;  // reuse as local placement cursor
    }
    __syncthreads();
    // pass B: place payload + its final global index into LDS
    for (int i = tid; i < ecnt; i += 4096) {
        int i1 = i + 1024, i2 = i + 2048, i3 = i + 3072;
        int d0 = dst[i];
        int s0 = src[i];
        int d1 = (i1 < ecnt) ? dst[i1] : 0;
        int s1 = (i1 < ecnt) ? src[i1] : 0;
        int d2 = (i2 < ecnt) ? dst[i2] : 0;
        int s2 = (i2 < ecnt) ? src[i2] : 0;
        int d3 = (i3 < ecnt) ? dst[i3] : 0;
        int s3 = (i3 < ecnt) ? src[i3] : 0;
        {
            int b = d0 / NPB, dl = d0 - b * NPB;
            int lp = atomicAdd(&cnt[b], 1);
            int p_ = lp + psum[b];
            int gp = gb[b] + lp;
            lds_pay[p_] = ((unsigned)dl << 17) | (unsigned)s0;
            lds_idx[p_] = (gp < CAP) ? (unsigned)(b * CAP + gp) : BADIDX;
        }
        if (i1 < ecnt) {
            int b = d1 / NPB, dl = d1 - b * NPB;
            int lp = atomicAdd(&cnt[b], 1);
            int p_ = lp + psum[b];
            int gp = gb[b] + lp;
            lds_pay[p_] = ((unsigned)dl << 17) | (unsigned)s1;
            lds_idx[p_] = (gp < CAP) ? (unsigned)(b * CAP + gp) : BADIDX;
        }
        if (i2 < ecnt) {
            int b = d2 / NPB, dl = d2 - b * NPB;
            int lp = atomicAdd(&cnt[b], 1);
            int p_ = lp + psum[b];
            int gp = gb[b] + lp;
            lds_pay[p_] = ((unsigned)dl << 17) | (unsigned)s2;
            lds_idx[p_] = (gp < CAP) ? (unsigned)(b * CAP + gp) : BADIDX;
        }
        if (i3 < ecnt) {
            int b = d3 / NPB, dl = d3 - b * NPB;
            int lp = atomicAdd(&cnt[b], 1);
            int p_ = lp + psum[b];
            int gp = gb[b] + lp;
            lds_pay[p_] = ((unsigned)dl << 17) | (unsigned)s3;
            lds_idx[p_] = (gp < CAP) ? (unsigned)(b * CAP + gp) : BADIDX;
        }
    }
    __syncthreads();
    // copy-out: coalesced LDS reads; idx is consecutive within each run
    for (int e = tid; e < ecnt; e += 1024) {
        unsigned int idx = lds_idx[e];
        if (idx != BADIDX) bdata[idx] = lds_pay[e];
    }
}

// per-bucket degree histogram -> xh[i] = fp16{di*x0, di*x1, di*x2, di}
__global__ void k_deg(const int* __restrict__ gcur, const unsigned int* __restrict__ bdata,
                      const float* __restrict__ x, __half2* __restrict__ xh) {
    __shared__ int cnt[NPB];
    int b = blockIdx.x, t = threadIdx.x;
    for (int j = t; j < NPB; j += 512) cnt[j] = 0;
    __syncthreads();
    int n = min(gcur[b], CAP);
    const unsigned int* p = bdata + (size_t)b * CAP;
    for (int e = t; e < n; e += 512) atomicAdd(&cnt[p[e] >> 17], 1);
    __syncthreads();
    int base = b * NPB;
    for (int j = t; j < NPB; j += 512) {
        int i = base + j;
        if (i < N_NODES) {
            float di = rsqrtf((float)cnt[j] + 1.0f);
            xh[2 * i + 0] = __floats2half2_rn(di * x[3 * i + 0], di * x[3 * i + 1]);
            xh[2 * i + 1] = __floats2half2_rn(di * x[3 * i + 2], di);
        }
    }
}

// layer-1: LDS fixed-point accumulate sum_s (di_s*x_s) via native ds_add_u32,
// 4-way ILP on the gather; fused W1/b1/relu/W2 -> th[i] = fp16{di*t[0..6], di}
__global__ void __launch_bounds__(1024) k_l1(
        const int* __restrict__ gcur, const unsigned int* __restrict__ bdata,
        const __half2* __restrict__ xh, const float* __restrict__ W1,
        const float* __restrict__ b1, const float* __restrict__ W2,
        uint4* __restrict__ th) {
    __shared__ int a[NPB * 3];
    int b = blockIdx.x, tid = threadIdx.x;
    for (int j = tid; j < NPB * 3; j += 1024) a[j] = 0;
    __syncthreads();
    int n = min(gcur[b], CAP);
    const unsigned int* p = bdata + (size_t)b * CAP;
    const uint2* xg = (const uint2*)xh;
    for (int e = tid; e < n; e += 4096) {
        int e1 = e + 1024, e2 = e + 2048, e3 = e + 3072;
        unsigned int pk0 = p[e];
        unsigned int pk1 = (e1 < n) ? p[e1] : 0u;
        unsigned int pk2 = (e2 < n) ? p[e2] : 0u;
        unsigned int pk3 = (e3 < n) ? p[e3] : 0u;
        uint2 g0 = xg[pk0 & 0x1FFFF];
        uint2 g1 = (e1 < n) ? xg[pk1 & 0x1FFFF] : make_uint2(0u, 0u);
        uint2 g2 = (e2 < n) ? xg[pk2 & 0x1FFFF] : make_uint2(0u, 0u);
        uint2 g3 = (e3 < n) ? xg[pk3 & 0x1FFFF] : make_uint2(0u, 0u);
        {
            int dl = pk0 >> 17;
            float2 f01 = h2f2(g0.x), f2w = h2f2(g0.y);
            atomicAdd(&a[dl * 3 + 0], fx(f01.x));
            atomicAdd(&a[dl * 3 + 1], fx(f01.y));
            atomicAdd(&a[dl * 3 + 2], fx(f2w.x));
        }
        if (e1 < n) {
            int dl = pk1 >> 17;
            float2 f01 = h2f2(g1.x), f2w = h2f2(g1.y);
            atomicAdd(&a[dl * 3 + 0], fx(f01.x));
            atomicAdd(&a[dl * 3 + 1], fx(f01.y));
            atomicAdd(&a[dl * 3 + 2], fx(f2w.x));
        }
        if (e2 < n) {
            int dl = pk2 >> 17;
            float2 f01 = h2f2(g2.x), f2w = h2f2(g2.y);
            atomicAdd(&a[dl * 3 + 0], fx(f01.x));
            atomicAdd(&a[dl * 3 + 1], fx(f01.y));
            atomicAdd(&a[dl * 3 + 2], fx(f2w.x));
        }
        if (e3 < n) {
            int dl = pk3 >> 17;
            float2 f01 = h2f2(g3.x), f2w = h2f2(g3.y);
            atomicAdd(&a[dl * 3 + 0], fx(f01.x));
            atomicAdd(&a[dl * 3 + 1], fx(f01.y));
            atomicAdd(&a[dl * 3 + 2], fx(f2w.x));
        }
    }
    __syncthreads();
    int base = b * NPB;
    for (int j = tid; j < NPB; j += 1024) {
        int i = base + j;
        if (i >= N_NODES) continue;
        uint2 gi = xg[i];
        float2 f01 = h2f2(gi.x);
        float2 f2w = h2f2(gi.y);
        float di = f2w.y;
        float a0 = di * ((float)a[j * 3 + 0] * INV_FSCALE + f01.x);
        float a1 = di * ((float)a[j * 3 + 1] * INV_FSCALE + f01.y);
        float a2 = di * ((float)a[j * 3 + 2] * INV_FSCALE + f2w.x);
        float r[16];
#pragma unroll
        for (int k = 0; k < 16; ++k)
            r[k] = fmaxf(a0 * W1[k] + a1 * W1[16 + k] + a2 * W1[32 + k] + b1[k], 0.0f);
        float t[7];
#pragma unroll
        for (int c = 0; c < 7; ++c) {
            float v = 0.0f;
#pragma unroll
            for (int k = 0; k < 16; ++k) v += r[k] * W2[7 * k + c];
            t[c] = di * v;
        }
        __half2 h0 = __floats2half2_rn(t[0], t[1]);
        __half2 h1 = __floats2half2_rn(t[2], t[3]);
        __half2 h2 = __floats2half2_rn(t[4], t[5]);
        __half2 h3 = __floats2half2_rn(t[6], di);
        uint4 pk;
        pk.x = *reinterpret_cast<unsigned int*>(&h0);
        pk.y = *reinterpret_cast<unsigned int*>(&h1);
        pk.z = *reinterpret_cast<unsigned int*>(&h2);
        pk.w = *reinterpret_cast<unsigned int*>(&h3);
        th[i] = pk;
    }
}

// layer-2: one 16B gather/edge with 4-way ILP, LDS fixed-point accumulate 7 values,
// then bias + log_softmax -> out
__global__ void __launch_bounds__(1024) k_l2(
        const int* __restrict__ gcur, const unsigned int* __restrict__ bdata,
        const uint4* __restrict__ th, const float* __restrict__ b2,
        float* __restrict__ out) {
    __shared__ int a[NPB * 7];
    int b = blockIdx.x, tid = threadIdx.x;
    for (int j = tid; j < NPB * 7; j += 1024) a[j] = 0;
    __syncthreads();
    int n = min(gcur[b], CAP);
    const unsigned int* p = bdata + (size_t)b * CAP;
    for (int e = tid; e < n; e += 4096) {
        int e1 = e + 1024, e2 = e + 2048, e3 = e + 3072;
        unsigned int pk0 = p[e];
        unsigned int pk1 = (e1 < n) ? p[e1] : 0u;
        unsigned int pk2 = (e2 < n) ? p[e2] : 0u;
        unsigned int pk3 = (e3 < n) ? p[e3] : 0u;
        uint4 g0 = th[pk0 & 0x1FFFF];
        uint4 g1 = (e1 < n) ? th[pk1 & 0x1FFFF] : make_uint4(0u, 0u, 0u, 0u);
        uint4 g2 = (e2 < n) ? th[pk2 & 0x1FFFF] : make_uint4(0u, 0u, 0u, 0u);
        uint4 g3 = (e3 < n) ? th[pk3 & 0x1FFFF] : make_uint4(0u, 0u, 0u, 0u);
        {
            int dl = pk0 >> 17;
            float2 u0 = h2f2(g0.x), u1 = h2f2(g0.y), u2 = h2f2(g0.z), u3 = h2f2(g0.w);
            atomicAdd(&a[dl * 7 + 0], fx(u0.x));
            atomicAdd(&a[dl * 7 + 1], fx(u0.y));
            atomicAdd(&a[dl * 7 + 2], fx(u1.x));
            atomicAdd(&a[dl * 7 + 3], fx(u1.y));
            atomicAdd(&a[dl * 7 + 4], fx(u2.x));
            atomicAdd(&a[dl * 7 + 5], fx(u2.y));
            atomicAdd(&a[dl * 7 + 6], fx(u3.x));
        }
        if (e1 < n) {
            int dl = pk1 >> 17;
            float2 u0 = h2f2(g1.x), u1 = h2f2(g1.y), u2 = h2f2(g1.z), u3 = h2f2(g1.w);
            atomicAdd(&a[dl * 7 + 0], fx(u0.x));
            atomicAdd(&a[dl * 7 + 1], fx(u0.y));
            atomicAdd(&a[dl * 7 + 2], fx(u1.x));
            atomicAdd(&a[dl * 7 + 3], fx(u1.y));
            atomicAdd(&a[dl * 7 + 4], fx(u2.x));
            atomicAdd(&a[dl * 7 + 5], fx(u2.y));
            atomicAdd(&a[dl * 7 + 6], fx(u3.x));
        }
        if (e2 < n) {
            int dl = pk2 >> 17;
            float2 u0 = h2f2(g2.x), u1 = h2f2(g2.y), u2 = h2f2(g2.z), u3 = h2f2(g2.w);
            atomicAdd(&a[dl * 7 + 0], fx(u0.x));
            atomicAdd(&a[dl * 7 + 1], fx(u0.y));
            atomicAdd(&a[dl * 7 + 2], fx(u1.x));
            atomicAdd(&a[dl * 7 + 3], fx(u1.y));
            atomicAdd(&a[dl * 7 + 4], fx(u2.x));
            atomicAdd(&a[dl * 7 + 5], fx(u2.y));
            atomicAdd(&a[dl * 7 + 6], fx(u3.x));
        }
        if (e3 < n) {
            int dl = pk3 >> 17;
            float2 u0 = h2f2(g3.x), u1 = h2f2(g3.y), u2 = h2f2(g3.z), u3 = h2f2(g3.w);
            atomicAdd(&a[dl * 7 + 0], fx(u0.x));
            atomicAdd(&a[dl * 7 + 1], fx(u0.y));
            atomicAdd(&a[dl * 7 + 2], fx(u1.x));
            atomicAdd(&a[dl * 7 + 3], fx(u1.y));
            atomicAdd(&a[dl * 7 + 4], fx(u2.x));
            atomicAdd(&a[dl * 7 + 5], fx(u2.y));
            atomicAdd(&a[dl * 7 + 6], fx(u3.x));
        }
    }
    __syncthreads();
    int base = b * NPB;
    for (int j = tid; j < NPB; j += 1024) {
        int i = base + j;
        if (i >= N_NODES) continue;
        uint4 gi = th[i];
        float2 t0 = h2f2(gi.x), t1 = h2f2(gi.y), t2 = h2f2(gi.z), t3 = h2f2(gi.w);
        float di = t3.y;
        float thv[7] = {t0.x, t0.y, t1.x, t1.y, t2.x, t2.y, t3.x};
        float v[7];
        float m = -1e30f;
#pragma unroll
        for (int c = 0; c < 7; ++c) {
            v[c] = di * ((float)a[j * 7 + c] * INV_FSCALE + thv[c]) + b2[c];
            m = fmaxf(m, v[c]);
        }
        float sum = 0.0f;
#pragma unroll
        for (int c = 0; c < 7; ++c) sum += expf(v[c] - m);
        float lse = m + logf(sum);
#pragma unroll
        for (int c = 0; c < 7; ++c) out[7 * i + c] = v[c] - lse;
    }
}

extern "C" void kernel_launch(void* const* d_in, const int* in_sizes, int n_in,
                              void* d_out, int out_size, void* d_ws, size_t ws_size,
                              hipStream_t stream) {
    const float* x  = (const float*)d_in[0];
    const int*   ei = (const int*)d_in[1];  // [2,E] flat int32: src then dst
    const float* W1 = (const float*)d_in[2];
    const float* b1 = (const float*)d_in[3];
    const float* W2 = (const float*)d_in[4];
    const float* b2 = (const float*)d_in[5];
    float* out = (float*)d_out;

    char* ws = (char*)d_ws;
    int*          gcur  = (int*)ws;          ws += 4096;                    // NB*4, 64B-aligned
    __half2*      xh    = (__half2*)ws;      ws += (size_t)N_NODES * 8;     // 0.8 MB
    uint4*        th    = (uint4*)ws;        ws += (size_t)N_NODES * 16;    // 1.6 MB
    unsigned int* bdata = (unsigned int*)ws;                                // 14.7 MB

    hipMemsetAsync(gcur, 0, NB * sizeof(int), stream);
    k_bucket<<<NBLK, 1024, 0, stream>>>(ei, gcur, bdata);
    k_deg<<<NB, 512, 0, stream>>>(gcur, bdata, x, xh);
    k_l1<<<NB, 1024, 0, stream>>>(gcur, bdata, xh, W1, b1, W2, th);
    k_l2<<<NB, 1024, 0, stream>>>(gcur, bdata, th, b2, out);
}